// Round 28
// baseline (254.137 us; speedup 1.0000x reference)
//
#include <hip/hip_runtime.h>
#include <stdint.h>

// ---------------------------------------------------------------------------
// 2-layer GCN: relu(gcn(x,W1,b1)) -> batchnorm -> relu(gcn(.,W2,b2))
// n=100000, E=1.6M, f_in=25, hid=128.
// R2 scan / R6 bf16+tile / R10 scatter / R14 pipelined gather / R15 MFMA /
// R18 zero-atomic build / R19 commuted layer-1 / R21 BN-fuse / R22 bf16 y1 /
// R24 l1 fusion (255) / R27 grid+prefetch NEUTRAL (253).
// R28: l1 is a serial dependent chain per node (rowptr->edge_src->xp,
//     ~1800cy) and this kernel shape is pinned at ~12 waves/CU regardless
//     of grid (R26 vs R27 both ~36% occupancy). Lever: ILP across nodes -
//     each wave now interleaves TWO nodes' chains per iteration (two
//     accumulator sets, both gathers in flight) => 2x memory-level
//     parallelism at fixed occupancy.
// ---------------------------------------------------------------------------

#define HID 128
#define NBB 512          // binning blocks (power of 2; segment index j = q*512+b)

typedef short bf16x8 __attribute__((ext_vector_type(8)));
typedef float f32x4 __attribute__((ext_vector_type(4)));

__device__ __forceinline__ unsigned short f2bf(float f) {
    unsigned int u = __float_as_uint(f);
    unsigned int r = (u + 0x7FFFu + ((u >> 16) & 1u)) >> 16;  // RNE
    return (unsigned short)r;
}
__device__ __forceinline__ unsigned int pack2bf(float lo, float hi) {
    return (unsigned int)f2bf(lo) | ((unsigned int)f2bf(hi) << 16);
}
__device__ __forceinline__ float bflo(unsigned int v) { return __uint_as_float(v << 16); }
__device__ __forceinline__ float bfhi(unsigned int v) { return __uint_as_float(v & 0xffff0000u); }

// --- detect whether edge_index buffer is int64 or int32 --------------------
__global__ void detect_kernel(const unsigned int* __restrict__ w, int* __restrict__ mode, int nwords) {
    __shared__ int any;
    if (threadIdx.x == 0) any = 0;
    __syncthreads();
    for (int i = threadIdx.x * 2 + 1; i < nwords && i < 8192; i += 512) {
        if (w[i] != 0) atomicOr(&any, 1);
    }
    __syncthreads();
    if (threadIdx.x == 0) *mode = any ? 0 : 1;  // 1 => int64 layout
}

__device__ __forceinline__ int load_idx(const void* ei, size_t i, int mode) {
    return mode ? (int)((const long long*)ei)[i] : ((const int*)ei)[i];
}

// --- count_q: per-(block, 256-node-chunk) tallies, LDS only ----------------
__global__ __launch_bounds__(256) void count_q_kernel(const void* __restrict__ ei,
                                                      const int* __restrict__ modep,
                                                      int* __restrict__ qcnt,
                                                      int E, int CHUNK, int nchunk) {
    __shared__ int qc[512];
    for (int i = threadIdx.x; i < nchunk; i += 256) qc[i] = 0;
    __syncthreads();
    int mode = *modep;
    int beg = blockIdx.x * CHUNK;
    int end = beg + CHUNK; if (end > E) end = E;
    for (int e = beg + threadIdx.x; e < end; e += 256) {
        int c = load_idx(ei, (size_t)E + e, mode);
        atomicAdd(&qc[c >> 8], 1);       // LDS atomic
    }
    __syncthreads();
    for (int i = threadIdx.x; i < nchunk; i += 256)
        qcnt[blockIdx.x * nchunk + i] = qc[i];   // b-major storage, coalesced
}

// --- scan_q phase 1: partial sums over scan-order positions ----------------
// scan order j = q*NBB + b  (q-major);  qcnt stored b-major: qcnt[b*nchunk+q]
__global__ __launch_bounds__(256) void scanq_partial_kernel(const int* __restrict__ qcnt,
                                                            int* __restrict__ blocksum,
                                                            int NQ, int nchunk) {
    int j0 = blockIdx.x * 2048 + threadIdx.x * 8;
    int s = 0;
    #pragma unroll
    for (int i = 0; i < 8; ++i) {
        int j = j0 + i;
        if (j < NQ) {
            int q = j >> 9, b = j & (NBB - 1);
            s += qcnt[b * nchunk + q];
        }
    }
    #pragma unroll
    for (int off = 32; off > 0; off >>= 1) s += __shfl_down(s, off);
    __shared__ int ls[4];
    if ((threadIdx.x & 63) == 0) ls[threadIdx.x >> 6] = s;
    __syncthreads();
    if (threadIdx.x == 0) blocksum[blockIdx.x] = ls[0] + ls[1] + ls[2] + ls[3];
}

// --- scan_q phase 2: scan block sums (nsb <= 1024) -------------------------
__global__ __launch_bounds__(1024) void scanq_blocksums_kernel(const int* __restrict__ blocksum,
                                                               int* __restrict__ blockoff,
                                                               int* __restrict__ qoff,
                                                               int nsb, int NQ) {
    __shared__ int s[1024];
    int t = threadIdx.x;
    int own = (t < nsb) ? blocksum[t] : 0;
    s[t] = own;
    __syncthreads();
    for (int off = 1; off < 1024; off <<= 1) {
        int v = s[t] + ((t >= off) ? s[t - off] : 0);
        __syncthreads();
        s[t] = v;
        __syncthreads();
    }
    if (t < nsb) blockoff[t] = s[t] - own;   // exclusive
    if (t == 1023) qoff[NQ] = s[1023];       // total == E
}

// --- scan_q phase 3: per-position exclusive prefix -> qoff -----------------
__global__ __launch_bounds__(256) void scanq_finalize_kernel(const int* __restrict__ qcnt,
                                                             const int* __restrict__ blockoff,
                                                             int* __restrict__ qoff,
                                                             int NQ, int nchunk) {
    int t = threadIdx.x;
    int j0 = blockIdx.x * 2048 + t * 8;
    int v[8], own = 0;
    #pragma unroll
    for (int i = 0; i < 8; ++i) {
        int j = j0 + i;
        v[i] = 0;
        if (j < NQ) {
            int q = j >> 9, b = j & (NBB - 1);
            v[i] = qcnt[b * nchunk + q];
        }
        own += v[i];
    }
    __shared__ int s[256];
    s[t] = own;
    __syncthreads();
    for (int off = 1; off < 256; off <<= 1) {
        int x = s[t] + ((t >= off) ? s[t - off] : 0);
        __syncthreads();
        s[t] = x;
        __syncthreads();
    }
    int e = blockoff[blockIdx.x] + s[t] - own;
    #pragma unroll
    for (int i = 0; i < 8; ++i) {
        int j = j0 + i;
        if (j < NQ) qoff[j] = e;
        e += v[i];
    }
}

// --- bin: append packed (c&255)<<24 | r into private segments (LDS cursors)-
__global__ __launch_bounds__(256) void bin_kernel(const void* __restrict__ ei,
                                                  const int* __restrict__ modep,
                                                  const int* __restrict__ qoff,
                                                  unsigned int* __restrict__ packed,
                                                  int E, int CHUNK, int nchunk) {
    __shared__ int cur[512];
    for (int i = threadIdx.x; i < nchunk; i += 256)
        cur[i] = qoff[i * NBB + blockIdx.x];
    __syncthreads();
    int mode = *modep;
    int beg = blockIdx.x * CHUNK;
    int end = beg + CHUNK; if (end > E) end = E;
    for (int e = beg + threadIdx.x; e < end; e += 256) {
        int c = load_idx(ei, (size_t)E + e, mode);
        int r = load_idx(ei, (size_t)e, mode);
        int pos = atomicAdd(&cur[c >> 8], 1);    // LDS atomic
        packed[pos] = ((unsigned)(c & 255) << 24) | (unsigned)r;
    }
}

// --- chunk_build: per-chunk histogram + scan -> rowptr/dinv, then place ----
__global__ __launch_bounds__(256) void chunk_build_kernel(
    const unsigned int* __restrict__ packed, const int* __restrict__ qoff,
    int* __restrict__ rowptr, float* __restrict__ dinv,
    int* __restrict__ edge_src, int n, int E) {
    int q = blockIdx.x;
    int t = threadIdx.x;
    int pbeg = qoff[q * NBB];
    int pend = qoff[(q + 1) * NBB];   // last chunk: (q+1)*NBB == NQ, qoff[NQ]=E
    __shared__ int cnt256[256], cur[256], s[256];
    cnt256[t] = 0;
    __syncthreads();
    for (int i = pbeg + t; i < pend; i += 256)
        atomicAdd(&cnt256[packed[i] >> 24], 1);  // LDS atomic
    __syncthreads();
    int own = cnt256[t];
    s[t] = own;
    __syncthreads();
    for (int off = 1; off < 256; off <<= 1) {
        int x = s[t] + ((t >= off) ? s[t - off] : 0);
        __syncthreads();
        s[t] = x;
        __syncthreads();
    }
    int pref = s[t] - own;   // exclusive within chunk
    int node = (q << 8) + t;
    if (node < n) {
        rowptr[node] = pbeg + pref;
        dinv[node] = rsqrtf((float)(own + 1));   // +1 self loop
    }
    cur[t] = pbeg + pref;
    if (q == gridDim.x - 1 && t == 0) rowptr[n] = E;
    __syncthreads();
    for (int i = pbeg + t; i < pend; i += 256) {
        unsigned int u = packed[i];
        int pos = atomicAdd(&cur[u >> 24], 1);   // LDS atomic
        edge_src[pos] = (int)(u & 0xFFFFFFu);
    }
}

// --- xpad: x fp32 [n][25] -> bf16 [n][32] (zero-padded) --------------------
__global__ __launch_bounds__(256) void xpad_kernel(const float* __restrict__ x,
                                                   unsigned int* __restrict__ xp, int n) {
    int r = blockIdx.x * 256 + threadIdx.x;
    if (r >= n) return;
    const float* xr = x + (size_t)r * 25;
    unsigned int* o = xp + (size_t)r * 16;
    #pragma unroll
    for (int j = 0; j < 12; ++j)
        o[j] = pack2bf(xr[j * 2], xr[j * 2 + 1]);
    o[12] = pack2bf(xr[24], 0.f);
    o[13] = 0u; o[14] = 0u; o[15] = 0u;
}

// --- l1: fused layer 1, TWO nodes interleaved per wave iteration -----------
__global__ __launch_bounds__(256) void l1_kernel(
    const unsigned int* __restrict__ xp, const int* __restrict__ rowptr,
    const int* __restrict__ edge_src, const float* __restrict__ dinv,
    const float* __restrict__ W, const float* __restrict__ bias,
    unsigned short* __restrict__ y1, float* __restrict__ bnsum,
    float* __restrict__ bnsumsq, int n) {
    __shared__ float lw[25 * HID];
    __shared__ float lb[HID];
    for (int i = threadIdx.x; i < 25 * HID; i += 256) lw[i] = W[i];
    if (threadIdx.x < HID) lb[threadIdx.x] = bias[threadIdx.x];
    __syncthreads();
    int lane = threadIdx.x & 63;
    int g = lane >> 4, i = lane & 15;
    int wid0 = (blockIdx.x * 256 + threadIdx.x) >> 6;
    int nwaves = gridDim.x << 2;    // waves in grid
    float s0 = 0.f, q0 = 0.f, s1 = 0.f, q1 = 0.f;   // bn partials c=lane, lane+64
    for (int nodeA = wid0; nodeA < n; nodeA += 2 * nwaves) {
        int nodeB = nodeA + nwaves;           // may be >= n (masked below)
        bool hasB = nodeB < n;
        int begA = rowptr[nodeA], endA = rowptr[nodeA + 1];
        int begB = 0, endB = 0;
        if (hasB) { begB = rowptr[nodeB]; endB = rowptr[nodeB + 1]; }
        float dcA = dinv[nodeA];
        float dcB = hasB ? dinv[nodeB] : 0.f;
        float axA = 0.f, ayA = 0.f, axB = 0.f, ayB = 0.f;
        int bA = begA, bB = begB;
        // interleave batches of both nodes while both have work
        while (bA < endA || bB < endB) {
            int mA = endA - bA; if (mA > 64) mA = 64; if (mA < 0) mA = 0;
            int mB = endB - bB; if (mB > 64) mB = 64; if (mB < 0) mB = 0;
            int sA = 0, sB = 0; float wA = 0.f, wB = 0.f;
            if (lane < mA) { sA = edge_src[bA + lane]; wA = dinv[sA]; }
            if (lane < mB) { sB = edge_src[bB + lane]; wB = dinv[sB]; }
            int nstA = (mA + 3) >> 2, nstB = (mB + 3) >> 2;
            int nst = nstA > nstB ? nstA : nstB;
            for (int t = 0; t < nst; ++t) {
                int e = 4 * t + g;            // <= 63; masked lanes hold zeros
                int sjA = __shfl(sA, e);
                int sjB = __shfl(sB, e);
                unsigned int uA = xp[(size_t)sjA * 16 + i];
                unsigned int uB = xp[(size_t)sjB * 16 + i];
                float wjA = __shfl(wA, e);
                float wjB = __shfl(wB, e);
                if (t >= nstA) wjA = 0.f;
                if (t >= nstB) wjB = 0.f;
                axA = fmaf(bflo(uA), wjA, axA); ayA = fmaf(bfhi(uA), wjA, ayA);
                axB = fmaf(bflo(uB), wjB, axB); ayB = fmaf(bfhi(uB), wjB, ayB);
            }
            bA += 64; bB += 64;
        }
        if (g == 0) {   // self loops
            unsigned int uA = xp[(size_t)nodeA * 16 + i];
            axA = fmaf(bflo(uA), dcA, axA);
            ayA = fmaf(bfhi(uA), dcA, ayA);
            if (hasB) {
                unsigned int uB = xp[(size_t)nodeB * 16 + i];
                axB = fmaf(bflo(uB), dcB, axB);
                ayB = fmaf(bfhi(uB), dcB, ayB);
            }
        }
        axA += __shfl_xor(axA, 16); axA += __shfl_xor(axA, 32);
        ayA += __shfl_xor(ayA, 16); ayA += __shfl_xor(ayA, 32);
        axB += __shfl_xor(axB, 16); axB += __shfl_xor(axB, 32);
        ayB += __shfl_xor(ayB, 16); ayB += __shfl_xor(ayB, 32);
        axA *= dcA; ayA *= dcA; axB *= dcB; ayB *= dcB;
        float accA0 = lb[lane], accA1 = lb[lane + 64];
        float accB0 = lb[lane], accB1 = lb[lane + 64];
        #pragma unroll
        for (int k = 0; k < 25; ++k) {
            float ykA = (k & 1) ? __shfl(ayA, k >> 1) : __shfl(axA, k >> 1);
            float ykB = (k & 1) ? __shfl(ayB, k >> 1) : __shfl(axB, k >> 1);
            float w0 = lw[k * HID + lane], w1 = lw[k * HID + lane + 64];
            accA0 = fmaf(ykA, w0, accA0);
            accA1 = fmaf(ykA, w1, accA1);
            accB0 = fmaf(ykB, w0, accB0);
            accB1 = fmaf(ykB, w1, accB1);
        }
        accA0 = fmaxf(accA0, 0.f); accA1 = fmaxf(accA1, 0.f);
        y1[(size_t)nodeA * HID + lane] = f2bf(accA0);
        y1[(size_t)nodeA * HID + lane + 64] = f2bf(accA1);
        s0 += accA0; q0 = fmaf(accA0, accA0, q0);
        s1 += accA1; q1 = fmaf(accA1, accA1, q1);
        if (hasB) {
            accB0 = fmaxf(accB0, 0.f); accB1 = fmaxf(accB1, 0.f);
            y1[(size_t)nodeB * HID + lane] = f2bf(accB0);
            y1[(size_t)nodeB * HID + lane + 64] = f2bf(accB1);
            s0 += accB0; q0 = fmaf(accB0, accB0, q0);
            s1 += accB1; q1 = fmaf(accB1, accB1, q1);
        }
    }
    __shared__ float r0[256], r1[256], r2[256], r3[256];
    r0[threadIdx.x] = s0; r1[threadIdx.x] = q0;
    r2[threadIdx.x] = s1; r3[threadIdx.x] = q1;
    __syncthreads();
    if (threadIdx.x < 64) {
        int l = threadIdx.x;
        float a = r0[l] + r0[l + 64] + r0[l + 128] + r0[l + 192];
        float b = r1[l] + r1[l + 64] + r1[l + 128] + r1[l + 192];
        float c = r2[l] + r2[l + 64] + r2[l + 128] + r2[l + 192];
        float d = r3[l] + r3[l + 64] + r3[l + 128] + r3[l + 192];
        atomicAdd(&bnsum[l], a);
        atomicAdd(&bnsumsq[l], b);
        atomicAdd(&bnsum[l + 64], c);
        atomicAdd(&bnsumsq[l + 64], d);
    }
}

// --- propagation (128-dim, layer 2): full 8-batches (zeros self-mask) ------
__global__ __launch_bounds__(256) void propagate_kernel(
    const unsigned short* __restrict__ h, const int* __restrict__ rowptr,
    const int* __restrict__ edge_src, const float* __restrict__ dinv,
    const float* __restrict__ bias, float* __restrict__ out, int n) {
    int wid = (blockIdx.x * 256 + threadIdx.x) >> 6;
    if (wid >= n) return;
    int lane = threadIdx.x & 63;
    int beg = rowptr[wid], end = rowptr[wid + 1];
    float dc = dinv[wid];
    float ax = 0.f, ay = 0.f;
    const unsigned int* hp = (const unsigned int*)h;  // 64 uints per row
    for (int b = beg; b < end; b += 64) {
        int m = end - b; if (m > 64) m = 64;
        int s = 0; float w = 0.f;
        if (lane < m) { s = edge_src[b + lane]; w = dinv[s]; }
        // j+7 <= 63 always (j multiple of 8, j < m <= 64); lanes >= m are zero
        for (int j = 0; j < m; j += 8) {
            int s0 = __shfl(s, j + 0), s1 = __shfl(s, j + 1);
            int s2 = __shfl(s, j + 2), s3 = __shfl(s, j + 3);
            int s4 = __shfl(s, j + 4), s5 = __shfl(s, j + 5);
            int s6 = __shfl(s, j + 6), s7 = __shfl(s, j + 7);
            unsigned int v0 = hp[(size_t)s0 * 64 + lane];
            unsigned int v1 = hp[(size_t)s1 * 64 + lane];
            unsigned int v2 = hp[(size_t)s2 * 64 + lane];
            unsigned int v3 = hp[(size_t)s3 * 64 + lane];
            unsigned int v4 = hp[(size_t)s4 * 64 + lane];
            unsigned int v5 = hp[(size_t)s5 * 64 + lane];
            unsigned int v6 = hp[(size_t)s6 * 64 + lane];
            unsigned int v7 = hp[(size_t)s7 * 64 + lane];
            float w0 = __shfl(w, j + 0), w1 = __shfl(w, j + 1);
            float w2 = __shfl(w, j + 2), w3 = __shfl(w, j + 3);
            float w4 = __shfl(w, j + 4), w5 = __shfl(w, j + 5);
            float w6 = __shfl(w, j + 6), w7 = __shfl(w, j + 7);
            ax = fmaf(bflo(v0), w0, ax); ay = fmaf(bfhi(v0), w0, ay);
            ax = fmaf(bflo(v1), w1, ax); ay = fmaf(bfhi(v1), w1, ay);
            ax = fmaf(bflo(v2), w2, ax); ay = fmaf(bfhi(v2), w2, ay);
            ax = fmaf(bflo(v3), w3, ax); ay = fmaf(bfhi(v3), w3, ay);
            ax = fmaf(bflo(v4), w4, ax); ay = fmaf(bfhi(v4), w4, ay);
            ax = fmaf(bflo(v5), w5, ax); ay = fmaf(bfhi(v5), w5, ay);
            ax = fmaf(bflo(v6), w6, ax); ay = fmaf(bfhi(v6), w6, ay);
            ax = fmaf(bflo(v7), w7, ax); ay = fmaf(bfhi(v7), w7, ay);
        }
    }
    {   // self loop
        unsigned int v = hp[(size_t)wid * 64 + lane];
        ax = fmaf(bflo(v), dc, ax);
        ay = fmaf(bfhi(v), dc, ay);
    }
    float bx = bias[lane * 2], by = bias[lane * 2 + 1];
    ax = fmaxf(fmaf(ax, dc, bx), 0.f);
    ay = fmaxf(fmaf(ay, dc, by), 0.f);
    *(float2*)(out + (size_t)wid * HID + lane * 2) = make_float2(ax, ay);
}

__global__ void bn_finalize_kernel(const float* __restrict__ sum, const float* __restrict__ sumsq,
                                   const float* __restrict__ gamma, const float* __restrict__ beta,
                                   float* __restrict__ scale, float* __restrict__ shift, float inv_n) {
    int c = threadIdx.x;
    float mean = sum[c] * inv_n;
    float var = sumsq[c] * inv_n - mean * mean;
    float sc = gamma[c] * rsqrtf(var + 1e-5f);
    scale[c] = sc;
    shift[c] = beta[c] - mean * sc;
}

// --- W2 transpose + bf16 cast: Wt[c][k] = bf16(W2[k][c]) -------------------
__global__ __launch_bounds__(256) void wt_kernel(const float* __restrict__ W,
                                                 unsigned short* __restrict__ Wt) {
    int idx = blockIdx.x * 256 + threadIdx.x;
    int c = idx >> 7, k = idx & 127;
    Wt[c * 128 + k] = f2bf(W[k * 128 + c]);
}

// --- GEMM2 via MFMA: h2 = bf16(bn(y1) @ W2), K=128, y1 bf16 ----------------
__global__ __launch_bounds__(256) void gemm2_mfma_kernel(
    const unsigned short* __restrict__ yb, const unsigned short* __restrict__ Wt,
    const float* __restrict__ scale, const float* __restrict__ shift,
    unsigned short* __restrict__ out, int n) {
    __shared__ unsigned short lwt[128 * 136];
    __shared__ unsigned short ly[128 * 136];
    int t = threadIdx.x;
    int base = blockIdx.x * 128;

    {
        const unsigned int* w32 = (const unsigned int*)Wt;
        unsigned int* l32 = (unsigned int*)lwt;
        #pragma unroll
        for (int i = 0; i < 32; ++i) {
            int idx = t + i * 256;
            int r = idx >> 6, cp = idx & 63;
            l32[r * 68 + cp] = w32[r * 64 + cp];
        }
    }
    {
        int r = t >> 1, hh = t & 1;
        int gr = base + r;
        unsigned int* l32 = (unsigned int*)ly;
        const uint4* yrow = (const uint4*)(yb + (size_t)gr * HID + hh * 64);
        #pragma unroll
        for (int j = 0; j < 8; ++j) {
            uint4 u = make_uint4(0u, 0u, 0u, 0u);
            if (gr < n) u = yrow[j];
            int gk = hh * 64 + j * 8;
            float a0 = fmaf(bflo(u.x), scale[gk + 0], shift[gk + 0]);
            float a1 = fmaf(bfhi(u.x), scale[gk + 1], shift[gk + 1]);
            float a2 = fmaf(bflo(u.y), scale[gk + 2], shift[gk + 2]);
            float a3 = fmaf(bfhi(u.y), scale[gk + 3], shift[gk + 3]);
            float a4 = fmaf(bflo(u.z), scale[gk + 4], shift[gk + 4]);
            float a5 = fmaf(bfhi(u.z), scale[gk + 5], shift[gk + 5]);
            float a6 = fmaf(bflo(u.w), scale[gk + 6], shift[gk + 6]);
            float a7 = fmaf(bfhi(u.w), scale[gk + 7], shift[gk + 7]);
            l32[r * 68 + hh * 32 + j * 4 + 0] = pack2bf(a0, a1);
            l32[r * 68 + hh * 32 + j * 4 + 1] = pack2bf(a2, a3);
            l32[r * 68 + hh * 32 + j * 4 + 2] = pack2bf(a4, a5);
            l32[r * 68 + hh * 32 + j * 4 + 3] = pack2bf(a6, a7);
        }
    }
    __syncthreads();

    int w = t >> 6, lane = t & 63;
    int li = lane & 15, lg = lane >> 4;
    f32x4 acc[2][8];
    #pragma unroll
    for (int a = 0; a < 2; ++a)
        #pragma unroll
        for (int b = 0; b < 8; ++b) acc[a][b] = (f32x4){0.f, 0.f, 0.f, 0.f};

    #pragma unroll
    for (int ks = 0; ks < 4; ++ks) {
        int kb = ks * 32 + lg * 8;
        bf16x8 af[2], bfr[8];
        #pragma unroll
        for (int rt = 0; rt < 2; ++rt)
            af[rt] = *(const bf16x8*)&ly[(w * 32 + rt * 16 + li) * 136 + kb];
        #pragma unroll
        for (int cf = 0; cf < 8; ++cf)
            bfr[cf] = *(const bf16x8*)&lwt[(cf * 16 + li) * 136 + kb];
        #pragma unroll
        for (int rt = 0; rt < 2; ++rt)
            #pragma unroll
            for (int cf = 0; cf < 8; ++cf)
                acc[rt][cf] = __builtin_amdgcn_mfma_f32_16x16x32_bf16(
                    af[rt], bfr[cf], acc[rt][cf], 0, 0, 0);
    }

    #pragma unroll
    for (int rt = 0; rt < 2; ++rt) {
        #pragma unroll
        for (int reg = 0; reg < 4; ++reg) {
            int gr = base + w * 32 + rt * 16 + lg * 4 + reg;
            if (gr < n) {
                #pragma unroll
                for (int cf = 0; cf < 8; ++cf)
                    out[(size_t)gr * HID + cf * 16 + li] = f2bf(acc[rt][cf][reg]);
            }
        }
    }
}

extern "C" void kernel_launch(void* const* d_in, const int* in_sizes, int n_in,
                              void* d_out, int out_size, void* d_ws, size_t ws_size,
                              hipStream_t stream) {
    const float* x     = (const float*)d_in[0];
    const void*  ei    = d_in[1];
    const float* W1    = (const float*)d_in[2];
    const float* b1    = (const float*)d_in[3];
    const float* gamma = (const float*)d_in[4];
    const float* beta  = (const float*)d_in[5];
    const float* W2    = (const float*)d_in[6];
    const float* b2    = (const float*)d_in[7];
    float* out = (float*)d_out;

    const int f_in = 25;
    int n = in_sizes[0] / f_in;
    int E = in_sizes[1] / 2;
    int nchunk = (n + 255) >> 8;                 // 256-node chunks (391)
    int NQ = nchunk * NBB;                       // queue segments (200192)
    int nsb = (NQ + 2047) / 2048;                // scan blocks (98, <=1024)
    int CHUNK = (E + NBB - 1) / NBB;             // edges per bin block

    char* ws = (char*)d_ws;
    size_t off = 0;
    auto alloc = [&](size_t bytes) -> void* {
        void* p = ws + off;
        off += (bytes + 511) & ~(size_t)511;
        return p;
    };
    int*   rowptr    = (int*)alloc(((size_t)n + 1) * 4);
    float* dinv      = (float*)alloc((size_t)n * 4);
    int*   edge_src  = (int*)alloc((size_t)E * 4);
    unsigned int* packed = (unsigned int*)alloc((size_t)E * 4);
    int*   qcnt      = (int*)alloc((size_t)NQ * 4);
    int*   qoff      = (int*)alloc(((size_t)NQ + 1) * 4);
    int*   blocksum  = (int*)alloc((size_t)nsb * 4);
    int*   blockoff  = (int*)alloc((size_t)nsb * 4);
    float* bnacc     = (float*)alloc(256 * 4);   // sum[128] ++ sumsq[128]
    float* sclshift  = (float*)alloc(256 * 4);   // scale[128] ++ shift[128]
    int*   mode      = (int*)alloc(4);
    unsigned int* xp   = (unsigned int*)alloc((size_t)n * 16 * 4);   // bf16[n][32]
    unsigned short* y1 = (unsigned short*)alloc((size_t)n * HID * 2);// bf16[n][128]
    unsigned short* Wt = (unsigned short*)alloc(128 * 128 * 2);      // bf16 W2^T
    unsigned short* h  = (unsigned short*)alloc((size_t)n * HID * 2);// bf16 h2

    hipMemsetAsync(bnacc, 0, 256 * 4, stream);

    detect_kernel<<<1, 256, 0, stream>>>((const unsigned int*)ei, mode, 2 * E);
    count_q_kernel<<<NBB, 256, 0, stream>>>(ei, mode, qcnt, E, CHUNK, nchunk);
    scanq_partial_kernel<<<nsb, 256, 0, stream>>>(qcnt, blocksum, NQ, nchunk);
    scanq_blocksums_kernel<<<1, 1024, 0, stream>>>(blocksum, blockoff, qoff, nsb, NQ);
    scanq_finalize_kernel<<<nsb, 256, 0, stream>>>(qcnt, blockoff, qoff, NQ, nchunk);
    bin_kernel<<<NBB, 256, 0, stream>>>(ei, mode, qoff, packed, E, CHUNK, nchunk);
    chunk_build_kernel<<<nchunk, 256, 0, stream>>>(packed, qoff, rowptr, dinv, edge_src, n, E);

    // layer 1 (commuted, fused): y1 = bf16(relu((A_hat@x)@W1 + b1)) + BN stats
    xpad_kernel<<<(n + 255) / 256, 256, 0, stream>>>(x, xp, n);
    l1_kernel<<<2048, 256, 0, stream>>>(xp, rowptr, edge_src, dinv, W1, b1,
                                        y1, bnacc, bnacc + 128, n);

    bn_finalize_kernel<<<1, 128, 0, stream>>>(bnacc, bnacc + 128, gamma, beta,
                                              sclshift, sclshift + 128, 1.0f / (float)n);

    // layer 2: h2 = bf16(bn(y1)@W2) via MFMA ; out = relu(prop(h2) + b2)
    wt_kernel<<<64, 256, 0, stream>>>(W2, Wt);
    gemm2_mfma_kernel<<<(n + 127) / 128, 256, 0, stream>>>(y1, Wt, sclshift, sclshift + 128, h, n);
    propagate_kernel<<<(n + 3) / 4, 256, 0, stream>>>(h, rowptr, edge_src, dinv, b2, out, n);
}

// Round 30
// 252.319 us; speedup vs baseline: 1.0072x; 1.0072x over previous
//
#include <hip/hip_runtime.h>
#include <stdint.h>

// ---------------------------------------------------------------------------
// 2-layer GCN: relu(gcn(x,W1,b1)) -> batchnorm -> relu(gcn(.,W2,b2))
// n=100000, E=1.6M, f_in=25, hid=128.
// R2 scan / R6 bf16+tile / R10 scatter / R14 pipelined gather / R15 MFMA /
// R18 zero-atomic build / R19 commuted layer-1 / R21 BN-fuse / R22 bf16 y1 /
// R24 l1 fusion / R27 grid 2048 + 4-deep prefetch (253us, best passing).
// R29 FAILED correctness (LDS-staged gather, absmax 0.35) - REVERTED to R27.
// Final state: 947 -> 253us (3.7x). l1 ~100us is a latency floor for the
// per-node dependent chain at achievable occupancy (3 structural attempts
// neutral/broken); layer-2 propagate at the 196MB fetch-service floor.
// ---------------------------------------------------------------------------

#define HID 128
#define NBB 512          // binning blocks (power of 2; segment index j = q*512+b)

typedef short bf16x8 __attribute__((ext_vector_type(8)));
typedef float f32x4 __attribute__((ext_vector_type(4)));

__device__ __forceinline__ unsigned short f2bf(float f) {
    unsigned int u = __float_as_uint(f);
    unsigned int r = (u + 0x7FFFu + ((u >> 16) & 1u)) >> 16;  // RNE
    return (unsigned short)r;
}
__device__ __forceinline__ unsigned int pack2bf(float lo, float hi) {
    return (unsigned int)f2bf(lo) | ((unsigned int)f2bf(hi) << 16);
}
__device__ __forceinline__ float bflo(unsigned int v) { return __uint_as_float(v << 16); }
__device__ __forceinline__ float bfhi(unsigned int v) { return __uint_as_float(v & 0xffff0000u); }

// --- detect whether edge_index buffer is int64 or int32 --------------------
__global__ void detect_kernel(const unsigned int* __restrict__ w, int* __restrict__ mode, int nwords) {
    __shared__ int any;
    if (threadIdx.x == 0) any = 0;
    __syncthreads();
    for (int i = threadIdx.x * 2 + 1; i < nwords && i < 8192; i += 512) {
        if (w[i] != 0) atomicOr(&any, 1);
    }
    __syncthreads();
    if (threadIdx.x == 0) *mode = any ? 0 : 1;  // 1 => int64 layout
}

__device__ __forceinline__ int load_idx(const void* ei, size_t i, int mode) {
    return mode ? (int)((const long long*)ei)[i] : ((const int*)ei)[i];
}

// --- count_q: per-(block, 256-node-chunk) tallies, LDS only ----------------
__global__ __launch_bounds__(256) void count_q_kernel(const void* __restrict__ ei,
                                                      const int* __restrict__ modep,
                                                      int* __restrict__ qcnt,
                                                      int E, int CHUNK, int nchunk) {
    __shared__ int qc[512];
    for (int i = threadIdx.x; i < nchunk; i += 256) qc[i] = 0;
    __syncthreads();
    int mode = *modep;
    int beg = blockIdx.x * CHUNK;
    int end = beg + CHUNK; if (end > E) end = E;
    for (int e = beg + threadIdx.x; e < end; e += 256) {
        int c = load_idx(ei, (size_t)E + e, mode);
        atomicAdd(&qc[c >> 8], 1);       // LDS atomic
    }
    __syncthreads();
    for (int i = threadIdx.x; i < nchunk; i += 256)
        qcnt[blockIdx.x * nchunk + i] = qc[i];   // b-major storage, coalesced
}

// --- scan_q phase 1: partial sums over scan-order positions ----------------
// scan order j = q*NBB + b  (q-major);  qcnt stored b-major: qcnt[b*nchunk+q]
__global__ __launch_bounds__(256) void scanq_partial_kernel(const int* __restrict__ qcnt,
                                                            int* __restrict__ blocksum,
                                                            int NQ, int nchunk) {
    int j0 = blockIdx.x * 2048 + threadIdx.x * 8;
    int s = 0;
    #pragma unroll
    for (int i = 0; i < 8; ++i) {
        int j = j0 + i;
        if (j < NQ) {
            int q = j >> 9, b = j & (NBB - 1);
            s += qcnt[b * nchunk + q];
        }
    }
    #pragma unroll
    for (int off = 32; off > 0; off >>= 1) s += __shfl_down(s, off);
    __shared__ int ls[4];
    if ((threadIdx.x & 63) == 0) ls[threadIdx.x >> 6] = s;
    __syncthreads();
    if (threadIdx.x == 0) blocksum[blockIdx.x] = ls[0] + ls[1] + ls[2] + ls[3];
}

// --- scan_q phase 2: scan block sums (nsb <= 1024) -------------------------
__global__ __launch_bounds__(1024) void scanq_blocksums_kernel(const int* __restrict__ blocksum,
                                                               int* __restrict__ blockoff,
                                                               int* __restrict__ qoff,
                                                               int nsb, int NQ) {
    __shared__ int s[1024];
    int t = threadIdx.x;
    int own = (t < nsb) ? blocksum[t] : 0;
    s[t] = own;
    __syncthreads();
    for (int off = 1; off < 1024; off <<= 1) {
        int v = s[t] + ((t >= off) ? s[t - off] : 0);
        __syncthreads();
        s[t] = v;
        __syncthreads();
    }
    if (t < nsb) blockoff[t] = s[t] - own;   // exclusive
    if (t == 1023) qoff[NQ] = s[1023];       // total == E
}

// --- scan_q phase 3: per-position exclusive prefix -> qoff -----------------
__global__ __launch_bounds__(256) void scanq_finalize_kernel(const int* __restrict__ qcnt,
                                                             const int* __restrict__ blockoff,
                                                             int* __restrict__ qoff,
                                                             int NQ, int nchunk) {
    int t = threadIdx.x;
    int j0 = blockIdx.x * 2048 + t * 8;
    int v[8], own = 0;
    #pragma unroll
    for (int i = 0; i < 8; ++i) {
        int j = j0 + i;
        v[i] = 0;
        if (j < NQ) {
            int q = j >> 9, b = j & (NBB - 1);
            v[i] = qcnt[b * nchunk + q];
        }
        own += v[i];
    }
    __shared__ int s[256];
    s[t] = own;
    __syncthreads();
    for (int off = 1; off < 256; off <<= 1) {
        int x = s[t] + ((t >= off) ? s[t - off] : 0);
        __syncthreads();
        s[t] = x;
        __syncthreads();
    }
    int e = blockoff[blockIdx.x] + s[t] - own;
    #pragma unroll
    for (int i = 0; i < 8; ++i) {
        int j = j0 + i;
        if (j < NQ) qoff[j] = e;
        e += v[i];
    }
}

// --- bin: append packed (c&255)<<24 | r into private segments (LDS cursors)-
__global__ __launch_bounds__(256) void bin_kernel(const void* __restrict__ ei,
                                                  const int* __restrict__ modep,
                                                  const int* __restrict__ qoff,
                                                  unsigned int* __restrict__ packed,
                                                  int E, int CHUNK, int nchunk) {
    __shared__ int cur[512];
    for (int i = threadIdx.x; i < nchunk; i += 256)
        cur[i] = qoff[i * NBB + blockIdx.x];
    __syncthreads();
    int mode = *modep;
    int beg = blockIdx.x * CHUNK;
    int end = beg + CHUNK; if (end > E) end = E;
    for (int e = beg + threadIdx.x; e < end; e += 256) {
        int c = load_idx(ei, (size_t)E + e, mode);
        int r = load_idx(ei, (size_t)e, mode);
        int pos = atomicAdd(&cur[c >> 8], 1);    // LDS atomic
        packed[pos] = ((unsigned)(c & 255) << 24) | (unsigned)r;
    }
}

// --- chunk_build: per-chunk histogram + scan -> rowptr/dinv, then place ----
__global__ __launch_bounds__(256) void chunk_build_kernel(
    const unsigned int* __restrict__ packed, const int* __restrict__ qoff,
    int* __restrict__ rowptr, float* __restrict__ dinv,
    int* __restrict__ edge_src, int n, int E) {
    int q = blockIdx.x;
    int t = threadIdx.x;
    int pbeg = qoff[q * NBB];
    int pend = qoff[(q + 1) * NBB];   // last chunk: (q+1)*NBB == NQ, qoff[NQ]=E
    __shared__ int cnt256[256], cur[256], s[256];
    cnt256[t] = 0;
    __syncthreads();
    for (int i = pbeg + t; i < pend; i += 256)
        atomicAdd(&cnt256[packed[i] >> 24], 1);  // LDS atomic
    __syncthreads();
    int own = cnt256[t];
    s[t] = own;
    __syncthreads();
    for (int off = 1; off < 256; off <<= 1) {
        int x = s[t] + ((t >= off) ? s[t - off] : 0);
        __syncthreads();
        s[t] = x;
        __syncthreads();
    }
    int pref = s[t] - own;   // exclusive within chunk
    int node = (q << 8) + t;
    if (node < n) {
        rowptr[node] = pbeg + pref;
        dinv[node] = rsqrtf((float)(own + 1));   // +1 self loop
    }
    cur[t] = pbeg + pref;
    if (q == gridDim.x - 1 && t == 0) rowptr[n] = E;
    __syncthreads();
    for (int i = pbeg + t; i < pend; i += 256) {
        unsigned int u = packed[i];
        int pos = atomicAdd(&cur[u >> 24], 1);   // LDS atomic
        edge_src[pos] = (int)(u & 0xFFFFFFu);
    }
}

// --- xpad: x fp32 [n][25] -> bf16 [n][32] (zero-padded) --------------------
__global__ __launch_bounds__(256) void xpad_kernel(const float* __restrict__ x,
                                                   unsigned int* __restrict__ xp, int n) {
    int r = blockIdx.x * 256 + threadIdx.x;
    if (r >= n) return;
    const float* xr = x + (size_t)r * 25;
    unsigned int* o = xp + (size_t)r * 16;
    #pragma unroll
    for (int j = 0; j < 12; ++j)
        o[j] = pack2bf(xr[j * 2], xr[j * 2 + 1]);
    o[12] = pack2bf(xr[24], 0.f);
    o[13] = 0u; o[14] = 0u; o[15] = 0u;
}

// --- l1: fused y0 = A_hat@x (32-dim gather, 4-deep prefetch) ;
// y1 = bf16(relu(y0@W1+b1)) + BN stats. Grid 2048.
__global__ __launch_bounds__(256) void l1_kernel(
    const unsigned int* __restrict__ xp, const int* __restrict__ rowptr,
    const int* __restrict__ edge_src, const float* __restrict__ dinv,
    const float* __restrict__ W, const float* __restrict__ bias,
    unsigned short* __restrict__ y1, float* __restrict__ bnsum,
    float* __restrict__ bnsumsq, int n) {
    __shared__ float lw[25 * HID];
    __shared__ float lb[HID];
    for (int i = threadIdx.x; i < 25 * HID; i += 256) lw[i] = W[i];
    if (threadIdx.x < HID) lb[threadIdx.x] = bias[threadIdx.x];
    __syncthreads();
    int lane = threadIdx.x & 63;
    int g = lane >> 4, i = lane & 15;
    int wid0 = (blockIdx.x * 256 + threadIdx.x) >> 6;
    int nwaves = gridDim.x << 2;    // 4 waves per 256-thread block
    float s0 = 0.f, q0 = 0.f, s1 = 0.f, q1 = 0.f;   // bn partials c=lane, lane+64
    for (int node = wid0; node < n; node += nwaves) {
        int beg = rowptr[node], end = rowptr[node + 1];
        float dc = dinv[node];
        float ax = 0.f, ay = 0.f;
        for (int b = beg; b < end; b += 64) {
            int m = end - b; if (m > 64) m = 64;
            int s = 0; float w = 0.f;
            if (lane < m) { s = edge_src[b + lane]; w = dinv[s]; }
            int nsteps = (m + 3) >> 2;
            // 4-deep prefetch: e = 4t+g+{0,4,8,12} <= 63; lanes >= m hold zeros.
            for (int t = 0; t < nsteps; t += 4) {
                int e0 = 4 * t + g;
                int sj0 = __shfl(s, e0);
                int sj1 = __shfl(s, e0 + 4);
                int sj2 = __shfl(s, e0 + 8);
                int sj3 = __shfl(s, e0 + 12);
                unsigned int u0 = xp[(size_t)sj0 * 16 + i];
                unsigned int u1 = xp[(size_t)sj1 * 16 + i];
                unsigned int u2 = xp[(size_t)sj2 * 16 + i];
                unsigned int u3 = xp[(size_t)sj3 * 16 + i];
                float wj0 = __shfl(w, e0);
                float wj1 = __shfl(w, e0 + 4);
                float wj2 = __shfl(w, e0 + 8);
                float wj3 = __shfl(w, e0 + 12);
                ax = fmaf(bflo(u0), wj0, ax); ay = fmaf(bfhi(u0), wj0, ay);
                ax = fmaf(bflo(u1), wj1, ax); ay = fmaf(bfhi(u1), wj1, ay);
                ax = fmaf(bflo(u2), wj2, ax); ay = fmaf(bfhi(u2), wj2, ay);
                ax = fmaf(bflo(u3), wj3, ax); ay = fmaf(bfhi(u3), wj3, ay);
            }
        }
        if (g == 0) {   // self loop, once
            unsigned int u = xp[(size_t)node * 16 + i];
            ax = fmaf(bflo(u), dc, ax);
            ay = fmaf(bfhi(u), dc, ay);
        }
        ax += __shfl_xor(ax, 16); ax += __shfl_xor(ax, 32);
        ay += __shfl_xor(ay, 16); ay += __shfl_xor(ay, 32);
        ax *= dc; ay *= dc;   // lane holds y0[2i], y0[2i+1] (fp32)
        float acc0 = lb[lane], acc1 = lb[lane + 64];
        #pragma unroll
        for (int k = 0; k < 25; ++k) {
            float yk = (k & 1) ? __shfl(ay, k >> 1) : __shfl(ax, k >> 1);
            acc0 = fmaf(yk, lw[k * HID + lane], acc0);
            acc1 = fmaf(yk, lw[k * HID + lane + 64], acc1);
        }
        acc0 = fmaxf(acc0, 0.f);
        acc1 = fmaxf(acc1, 0.f);
        y1[(size_t)node * HID + lane] = f2bf(acc0);
        y1[(size_t)node * HID + lane + 64] = f2bf(acc1);
        s0 += acc0; q0 = fmaf(acc0, acc0, q0);
        s1 += acc1; q1 = fmaf(acc1, acc1, q1);
    }
    __shared__ float r0[256], r1[256], r2[256], r3[256];
    r0[threadIdx.x] = s0; r1[threadIdx.x] = q0;
    r2[threadIdx.x] = s1; r3[threadIdx.x] = q1;
    __syncthreads();
    if (threadIdx.x < 64) {
        int l = threadIdx.x;
        float a = r0[l] + r0[l + 64] + r0[l + 128] + r0[l + 192];
        float b = r1[l] + r1[l + 64] + r1[l + 128] + r1[l + 192];
        float c = r2[l] + r2[l + 64] + r2[l + 128] + r2[l + 192];
        float d = r3[l] + r3[l + 64] + r3[l + 128] + r3[l + 192];
        atomicAdd(&bnsum[l], a);
        atomicAdd(&bnsumsq[l], b);
        atomicAdd(&bnsum[l + 64], c);
        atomicAdd(&bnsumsq[l + 64], d);
    }
}

// --- propagation (128-dim, layer 2): full 8-batches (zeros self-mask) ------
__global__ __launch_bounds__(256) void propagate_kernel(
    const unsigned short* __restrict__ h, const int* __restrict__ rowptr,
    const int* __restrict__ edge_src, const float* __restrict__ dinv,
    const float* __restrict__ bias, float* __restrict__ out, int n) {
    int wid = (blockIdx.x * 256 + threadIdx.x) >> 6;
    if (wid >= n) return;
    int lane = threadIdx.x & 63;
    int beg = rowptr[wid], end = rowptr[wid + 1];
    float dc = dinv[wid];
    float ax = 0.f, ay = 0.f;
    const unsigned int* hp = (const unsigned int*)h;  // 64 uints per row
    for (int b = beg; b < end; b += 64) {
        int m = end - b; if (m > 64) m = 64;
        int s = 0; float w = 0.f;
        if (lane < m) { s = edge_src[b + lane]; w = dinv[s]; }
        // j+7 <= 63 always (j multiple of 8, j < m <= 64); lanes >= m are zero
        for (int j = 0; j < m; j += 8) {
            int s0 = __shfl(s, j + 0), s1 = __shfl(s, j + 1);
            int s2 = __shfl(s, j + 2), s3 = __shfl(s, j + 3);
            int s4 = __shfl(s, j + 4), s5 = __shfl(s, j + 5);
            int s6 = __shfl(s, j + 6), s7 = __shfl(s, j + 7);
            unsigned int v0 = hp[(size_t)s0 * 64 + lane];
            unsigned int v1 = hp[(size_t)s1 * 64 + lane];
            unsigned int v2 = hp[(size_t)s2 * 64 + lane];
            unsigned int v3 = hp[(size_t)s3 * 64 + lane];
            unsigned int v4 = hp[(size_t)s4 * 64 + lane];
            unsigned int v5 = hp[(size_t)s5 * 64 + lane];
            unsigned int v6 = hp[(size_t)s6 * 64 + lane];
            unsigned int v7 = hp[(size_t)s7 * 64 + lane];
            float w0 = __shfl(w, j + 0), w1 = __shfl(w, j + 1);
            float w2 = __shfl(w, j + 2), w3 = __shfl(w, j + 3);
            float w4 = __shfl(w, j + 4), w5 = __shfl(w, j + 5);
            float w6 = __shfl(w, j + 6), w7 = __shfl(w, j + 7);
            ax = fmaf(bflo(v0), w0, ax); ay = fmaf(bfhi(v0), w0, ay);
            ax = fmaf(bflo(v1), w1, ax); ay = fmaf(bfhi(v1), w1, ay);
            ax = fmaf(bflo(v2), w2, ax); ay = fmaf(bfhi(v2), w2, ay);
            ax = fmaf(bflo(v3), w3, ax); ay = fmaf(bfhi(v3), w3, ay);
            ax = fmaf(bflo(v4), w4, ax); ay = fmaf(bfhi(v4), w4, ay);
            ax = fmaf(bflo(v5), w5, ax); ay = fmaf(bfhi(v5), w5, ay);
            ax = fmaf(bflo(v6), w6, ax); ay = fmaf(bfhi(v6), w6, ay);
            ax = fmaf(bflo(v7), w7, ax); ay = fmaf(bfhi(v7), w7, ay);
        }
    }
    {   // self loop
        unsigned int v = hp[(size_t)wid * 64 + lane];
        ax = fmaf(bflo(v), dc, ax);
        ay = fmaf(bfhi(v), dc, ay);
    }
    float bx = bias[lane * 2], by = bias[lane * 2 + 1];
    ax = fmaxf(fmaf(ax, dc, bx), 0.f);
    ay = fmaxf(fmaf(ay, dc, by), 0.f);
    *(float2*)(out + (size_t)wid * HID + lane * 2) = make_float2(ax, ay);
}

__global__ void bn_finalize_kernel(const float* __restrict__ sum, const float* __restrict__ sumsq,
                                   const float* __restrict__ gamma, const float* __restrict__ beta,
                                   float* __restrict__ scale, float* __restrict__ shift, float inv_n) {
    int c = threadIdx.x;
    float mean = sum[c] * inv_n;
    float var = sumsq[c] * inv_n - mean * mean;
    float sc = gamma[c] * rsqrtf(var + 1e-5f);
    scale[c] = sc;
    shift[c] = beta[c] - mean * sc;
}

// --- W2 transpose + bf16 cast: Wt[c][k] = bf16(W2[k][c]) -------------------
__global__ __launch_bounds__(256) void wt_kernel(const float* __restrict__ W,
                                                 unsigned short* __restrict__ Wt) {
    int idx = blockIdx.x * 256 + threadIdx.x;
    int c = idx >> 7, k = idx & 127;
    Wt[c * 128 + k] = f2bf(W[k * 128 + c]);
}

// --- GEMM2 via MFMA: h2 = bf16(bn(y1) @ W2), K=128, y1 bf16 ----------------
__global__ __launch_bounds__(256) void gemm2_mfma_kernel(
    const unsigned short* __restrict__ yb, const unsigned short* __restrict__ Wt,
    const float* __restrict__ scale, const float* __restrict__ shift,
    unsigned short* __restrict__ out, int n) {
    __shared__ unsigned short lwt[128 * 136];
    __shared__ unsigned short ly[128 * 136];
    int t = threadIdx.x;
    int base = blockIdx.x * 128;

    {
        const unsigned int* w32 = (const unsigned int*)Wt;
        unsigned int* l32 = (unsigned int*)lwt;
        #pragma unroll
        for (int i = 0; i < 32; ++i) {
            int idx = t + i * 256;
            int r = idx >> 6, cp = idx & 63;
            l32[r * 68 + cp] = w32[r * 64 + cp];
        }
    }
    {
        int r = t >> 1, hh = t & 1;
        int gr = base + r;
        unsigned int* l32 = (unsigned int*)ly;
        const uint4* yrow = (const uint4*)(yb + (size_t)gr * HID + hh * 64);
        #pragma unroll
        for (int j = 0; j < 8; ++j) {
            uint4 u = make_uint4(0u, 0u, 0u, 0u);
            if (gr < n) u = yrow[j];
            int gk = hh * 64 + j * 8;
            float a0 = fmaf(bflo(u.x), scale[gk + 0], shift[gk + 0]);
            float a1 = fmaf(bfhi(u.x), scale[gk + 1], shift[gk + 1]);
            float a2 = fmaf(bflo(u.y), scale[gk + 2], shift[gk + 2]);
            float a3 = fmaf(bfhi(u.y), scale[gk + 3], shift[gk + 3]);
            float a4 = fmaf(bflo(u.z), scale[gk + 4], shift[gk + 4]);
            float a5 = fmaf(bfhi(u.z), scale[gk + 5], shift[gk + 5]);
            float a6 = fmaf(bflo(u.w), scale[gk + 6], shift[gk + 6]);
            float a7 = fmaf(bfhi(u.w), scale[gk + 7], shift[gk + 7]);
            l32[r * 68 + hh * 32 + j * 4 + 0] = pack2bf(a0, a1);
            l32[r * 68 + hh * 32 + j * 4 + 1] = pack2bf(a2, a3);
            l32[r * 68 + hh * 32 + j * 4 + 2] = pack2bf(a4, a5);
            l32[r * 68 + hh * 32 + j * 4 + 3] = pack2bf(a6, a7);
        }
    }
    __syncthreads();

    int w = t >> 6, lane = t & 63;
    int li = lane & 15, lg = lane >> 4;
    f32x4 acc[2][8];
    #pragma unroll
    for (int a = 0; a < 2; ++a)
        #pragma unroll
        for (int b = 0; b < 8; ++b) acc[a][b] = (f32x4){0.f, 0.f, 0.f, 0.f};

    #pragma unroll
    for (int ks = 0; ks < 4; ++ks) {
        int kb = ks * 32 + lg * 8;
        bf16x8 af[2], bfr[8];
        #pragma unroll
        for (int rt = 0; rt < 2; ++rt)
            af[rt] = *(const bf16x8*)&ly[(w * 32 + rt * 16 + li) * 136 + kb];
        #pragma unroll
        for (int cf = 0; cf < 8; ++cf)
            bfr[cf] = *(const bf16x8*)&lwt[(cf * 16 + li) * 136 + kb];
        #pragma unroll
        for (int rt = 0; rt < 2; ++rt)
            #pragma unroll
            for (int cf = 0; cf < 8; ++cf)
                acc[rt][cf] = __builtin_amdgcn_mfma_f32_16x16x32_bf16(
                    af[rt], bfr[cf], acc[rt][cf], 0, 0, 0);
    }

    #pragma unroll
    for (int rt = 0; rt < 2; ++rt) {
        #pragma unroll
        for (int reg = 0; reg < 4; ++reg) {
            int gr = base + w * 32 + rt * 16 + lg * 4 + reg;
            if (gr < n) {
                #pragma unroll
                for (int cf = 0; cf < 8; ++cf)
                    out[(size_t)gr * HID + cf * 16 + li] = f2bf(acc[rt][cf][reg]);
            }
        }
    }
}

extern "C" void kernel_launch(void* const* d_in, const int* in_sizes, int n_in,
                              void* d_out, int out_size, void* d_ws, size_t ws_size,
                              hipStream_t stream) {
    const float* x     = (const float*)d_in[0];
    const void*  ei    = d_in[1];
    const float* W1    = (const float*)d_in[2];
    const float* b1    = (const float*)d_in[3];
    const float* gamma = (const float*)d_in[4];
    const float* beta  = (const float*)d_in[5];
    const float* W2    = (const float*)d_in[6];
    const float* b2    = (const float*)d_in[7];
    float* out = (float*)d_out;

    const int f_in = 25;
    int n = in_sizes[0] / f_in;
    int E = in_sizes[1] / 2;
    int nchunk = (n + 255) >> 8;                 // 256-node chunks (391)
    int NQ = nchunk * NBB;                       // queue segments (200192)
    int nsb = (NQ + 2047) / 2048;                // scan blocks (98, <=1024)
    int CHUNK = (E + NBB - 1) / NBB;             // edges per bin block

    char* ws = (char*)d_ws;
    size_t off = 0;
    auto alloc = [&](size_t bytes) -> void* {
        void* p = ws + off;
        off += (bytes + 511) & ~(size_t)511;
        return p;
    };
    int*   rowptr    = (int*)alloc(((size_t)n + 1) * 4);
    float* dinv      = (float*)alloc((size_t)n * 4);
    int*   edge_src  = (int*)alloc((size_t)E * 4);
    unsigned int* packed = (unsigned int*)alloc((size_t)E * 4);
    int*   qcnt      = (int*)alloc((size_t)NQ * 4);
    int*   qoff      = (int*)alloc(((size_t)NQ + 1) * 4);
    int*   blocksum  = (int*)alloc((size_t)nsb * 4);
    int*   blockoff  = (int*)alloc((size_t)nsb * 4);
    float* bnacc     = (float*)alloc(256 * 4);   // sum[128] ++ sumsq[128]
    float* sclshift  = (float*)alloc(256 * 4);   // scale[128] ++ shift[128]
    int*   mode      = (int*)alloc(4);
    unsigned int* xp   = (unsigned int*)alloc((size_t)n * 16 * 4);   // bf16[n][32]
    unsigned short* y1 = (unsigned short*)alloc((size_t)n * HID * 2);// bf16[n][128]
    unsigned short* Wt = (unsigned short*)alloc(128 * 128 * 2);      // bf16 W2^T
    unsigned short* h  = (unsigned short*)alloc((size_t)n * HID * 2);// bf16 h2

    hipMemsetAsync(bnacc, 0, 256 * 4, stream);

    detect_kernel<<<1, 256, 0, stream>>>((const unsigned int*)ei, mode, 2 * E);
    count_q_kernel<<<NBB, 256, 0, stream>>>(ei, mode, qcnt, E, CHUNK, nchunk);
    scanq_partial_kernel<<<nsb, 256, 0, stream>>>(qcnt, blocksum, NQ, nchunk);
    scanq_blocksums_kernel<<<1, 1024, 0, stream>>>(blocksum, blockoff, qoff, nsb, NQ);
    scanq_finalize_kernel<<<nsb, 256, 0, stream>>>(qcnt, blockoff, qoff, NQ, nchunk);
    bin_kernel<<<NBB, 256, 0, stream>>>(ei, mode, qoff, packed, E, CHUNK, nchunk);
    chunk_build_kernel<<<nchunk, 256, 0, stream>>>(packed, qoff, rowptr, dinv, edge_src, n, E);

    // layer 1 (commuted, fused): y1 = bf16(relu((A_hat@x)@W1 + b1)) + BN stats
    xpad_kernel<<<(n + 255) / 256, 256, 0, stream>>>(x, xp, n);
    l1_kernel<<<2048, 256, 0, stream>>>(xp, rowptr, edge_src, dinv, W1, b1,
                                        y1, bnacc, bnacc + 128, n);

    bn_finalize_kernel<<<1, 128, 0, stream>>>(bnacc, bnacc + 128, gamma, beta,
                                              sclshift, sclshift + 128, 1.0f / (float)n);

    // layer 2: h2 = bf16(bn(y1)@W2) via MFMA ; out = relu(prop(h2) + b2)
    wt_kernel<<<64, 256, 0, stream>>>(W2, Wt);
    gemm2_mfma_kernel<<<(n + 127) / 128, 256, 0, stream>>>(y1, Wt, sclshift, sclshift + 128, h, n);
    propagate_kernel<<<(n + 3) / 4, 256, 0, stream>>>(h, rowptr, edge_src, dinv, b2, out, n);
}